// Round 4
// baseline (487.699 us; speedup 1.0000x reference)
//
#include <hip/hip_runtime.h>
#include <math.h>

#define S 8192
#define D 768
#define NA 256
#define NO 256
#define MAXW 40
#define NCAT 13
#define NPOL 3
#define NPROJ (2 + NCAT + NPOL)   // 18 projection columns: [valid0,valid1, cat0..12, pol0..2]

// out layout (flat fp32, reference return order)
#define OFF1 ((size_t)NA * NO * 2 * D)            // asp_ids
#define OFF2 (OFF1 + (size_t)NA * NO)             // opi_ids
#define OFF3 (OFF2 + (size_t)NA * NO)             // cate_out
#define OFF4 (OFF3 + (size_t)NA * NO * NCAT)      // polar_out
#define OFF5 (OFF4 + (size_t)NA * NO * NPOL)      // valid_mask

typedef float vfloat4 __attribute__((ext_vector_type(4)));
typedef int   vint4   __attribute__((ext_vector_type(4)));

static __device__ __forceinline__ vfloat4 vmax4(vfloat4 a, vfloat4 b) {
    vfloat4 r;
    r.x = fmaxf(a.x, b.x); r.y = fmaxf(a.y, b.y);
    r.z = fmaxf(a.z, b.z); r.w = fmaxf(a.w, b.w);
    return r;
}

// ---------------------------------------------------------------------------
// Kernel 1: per-span max-pool (float4 loads, 192 active lanes, row loop
// unrolled x4 for MLP) + double-precision projection partials.
// One block per span (0..255 asp, 256..511 opi).
// ---------------------------------------------------------------------------
__global__ __launch_bounds__(256) void span_pool_proj(
    const float* __restrict__ word_rep,
    const int*   __restrict__ aspects,
    const int*   __restrict__ opinions,
    const float* __restrict__ W_valid,   // (1536,2) row-major
    const float* __restrict__ W_cat,     // (1536,13)
    const float* __restrict__ W_pol,     // (1536,3)
    float*  __restrict__ rep_out,
    double* __restrict__ proj_out)
{
    __shared__ float rep[D];
    const int b = blockIdx.x;     // 0..511
    const int t = threadIdx.x;    // 0..255

    const int* spans = (b < NA) ? aspects : opinions;
    const int  s     = (b < NA) ? b : (b - NA);
    const int  woff  = (b < NA) ? 0 : D;

    const int head  = spans[2 * s];
    const int tail  = spans[2 * s + 1];
    const int width = tail - head;         // 1..40; all rows in-bounds (head <= S-MAXW-1)

    if (t < 192) {
        const vfloat4* base = (const vfloat4*)(word_rep + (size_t)head * D) + t;
        vfloat4 m = base[0];
        int r = 1;
        for (; r + 3 < width; r += 4) {    // 4 independent loads in flight
            vfloat4 v0 = base[(size_t)(r)     * (D / 4)];
            vfloat4 v1 = base[(size_t)(r + 1) * (D / 4)];
            vfloat4 v2 = base[(size_t)(r + 2) * (D / 4)];
            vfloat4 v3 = base[(size_t)(r + 3) * (D / 4)];
            m = vmax4(m, vmax4(vmax4(v0, v1), vmax4(v2, v3)));
        }
        for (; r < width; ++r)
            m = vmax4(m, base[(size_t)r * (D / 4)]);
        ((vfloat4*)rep)[t] = m;
        ((vfloat4*)(rep_out + (size_t)b * D))[t] = m;
    }
    __syncthreads();

    if (t < NPROJ) {
        const float* W; int ncol, col;
        if (t < 2)             { W = W_valid; ncol = 2;    col = t; }
        else if (t < 2 + NCAT) { W = W_cat;   ncol = NCAT; col = t - 2; }
        else                   { W = W_pol;   ncol = NPOL; col = t - 2 - NCAT; }
        double a0 = 0.0, a1 = 0.0;   // 2 accumulators to break the dep chain
        for (int d = 0; d < D; d += 2) {
            a0 += (double)rep[d]     * (double)W[(size_t)(woff + d)     * ncol + col];
            a1 += (double)rep[d + 1] * (double)W[(size_t)(woff + d + 1) * ncol + col];
        }
        proj_out[(size_t)b * NPROJ + t] = a0 + a1;
    }
}

// ---------------------------------------------------------------------------
// Kernel 2: per-pair mask + small outputs. Grid 256 blocks (i) x 256 thr (j).
// Writes mask[p] to ws for the streaming kernel.
// ---------------------------------------------------------------------------
__global__ __launch_bounds__(256) void pair_small(
    const double* __restrict__ proj,     // 512 x 18
    const float*  __restrict__ b_valid,
    const float*  __restrict__ b_cat,
    const float*  __restrict__ b_pol,
    float*    __restrict__ out,
    unsigned* __restrict__ maskbuf)
{
    const int i = blockIdx.x;
    const int j = threadIdx.x;
    const int p = (i << 8) | j;

    const double* pa = proj + (size_t)i * NPROJ;          // wave-uniform -> scalar loads
    const double* po = proj + (size_t)(NA + j) * NPROJ;

    const double v0 = pa[0] + po[0] + (double)b_valid[0];
    const double v1 = pa[1] + po[1] + (double)b_valid[1];
    const int mask = (v0 > v1) ? 1 : 0;

    maskbuf[p] = (unsigned)mask;
    out[OFF1 + p] = mask ? (float)i : -1.0f;
    out[OFF2 + p] = mask ? (float)j : -1.0f;
    out[OFF5 + p] = mask ? 1.0f : 0.0f;
#pragma unroll
    for (int c = 0; c < NCAT; ++c) {
        float v = mask ? (float)(pa[2 + c] + po[2 + c] + (double)b_cat[c]) : 0.0f;
        out[OFF3 + (size_t)p * NCAT + c] = v;
    }
#pragma unroll
    for (int c = 0; c < NPOL; ++c) {
        float v = mask ? (float)(pa[2 + NCAT + c] + po[2 + NCAT + c] + (double)b_pol[c]) : 0.0f;
        out[OFF4 + (size_t)p * NPOL + c] = v;
    }
}

// ---------------------------------------------------------------------------
// Kernel 3: streaming write of out0 (402.6 MB). One block per 8 consecutive
// pairs (same aspect i, opinions j0..j0+7). 384 lanes; each lane emits 8
// independent nontemporal float4 stores into a 48 KB contiguous region.
// Opinion fragments are loaded unconditionally (L2-hot) to avoid branch-
// dependent load chains; mask applied via select.
// ---------------------------------------------------------------------------
#define KROWS 8
__global__ __launch_bounds__(384) void pair_stream(
    const vfloat4*  __restrict__ rep4,     // 512 rows x 192 float4
    const unsigned* __restrict__ maskbuf,
    vfloat4*        __restrict__ out4)
{
    const int b  = blockIdx.x;    // 0..8191
    const int t  = threadIdx.x;   // 0..383
    const int p0 = b * KROWS;
    const int i  = p0 >> 8;       // constant over the block (KROWS divides 256)
    const int j0 = p0 & 255;

    const vint4* mb = (const vint4*)(maskbuf + p0);   // 32B aligned, wave-uniform
    const vint4 ma = mb[0], mc = mb[1];
    const int mk[KROWS] = { ma.x, ma.y, ma.z, ma.w, mc.x, mc.y, mc.z, mc.w };

    vfloat4 vals[KROWS];
    if (t < 192) {
        const vfloat4 a = rep4[(size_t)i * 192 + t];
#pragma unroll
        for (int r = 0; r < KROWS; ++r) vals[r] = a;
    } else {
#pragma unroll
        for (int r = 0; r < KROWS; ++r)     // 8 independent L2-hot loads
            vals[r] = rep4[(size_t)(NA + j0 + r) * 192 + (t - 192)];
    }

#pragma unroll
    for (int r = 0; r < KROWS; ++r) {
        const vfloat4 v = mk[r] ? vals[r] : (vfloat4)0.f;
        __builtin_nontemporal_store(v, &out4[((size_t)p0 + r) * 384 + t]);
    }
}

extern "C" void kernel_launch(void* const* d_in, const int* in_sizes, int n_in,
                              void* d_out, int out_size, void* d_ws, size_t ws_size,
                              hipStream_t stream)
{
    const float* word_rep = (const float*)d_in[0];   // (8192,768)
    const int*   aspects  = (const int*)  d_in[1];   // (256,2)
    const int*   opinions = (const int*)  d_in[2];   // (256,2)
    const float* W_valid  = (const float*)d_in[3];   // (1536,2)
    const float* b_valid  = (const float*)d_in[4];   // (2,)
    const float* W_cat    = (const float*)d_in[5];   // (1536,13)
    const float* b_cat    = (const float*)d_in[6];   // (13,)
    const float* W_pol    = (const float*)d_in[7];   // (1536,3)
    const float* b_pol    = (const float*)d_in[8];   // (3,)
    float* out = (float*)d_out;

    // ws layout: rep (512*768 f32 = 1.5 MB) | proj (512*18 f64) | mask (64K u32)
    float*    rep  = (float*)d_ws;
    double*   proj = (double*)((char*)d_ws + (size_t)(NA + NO) * D * sizeof(float));
    unsigned* mask = (unsigned*)((char*)proj + (size_t)(NA + NO) * NPROJ * sizeof(double));

    span_pool_proj<<<NA + NO, 256, 0, stream>>>(
        word_rep, aspects, opinions, W_valid, W_cat, W_pol, rep, proj);

    pair_small<<<NA, NO, 0, stream>>>(proj, b_valid, b_cat, b_pol, out, mask);

    pair_stream<<<(NA * NO) / KROWS, 384, 0, stream>>>(
        (const vfloat4*)rep, mask, (vfloat4*)out);
}